// Round 1
// baseline (140.814 us; speedup 1.0000x reference)
//
#include <hip/hip_runtime.h>
#include <math.h>

#define NB   16      // batches
#define NP   4096    // points per cloud (N == M)
#define ILP  4       // x-points per thread
#define BLK  256     // threads per block
#define TILE 512     // y-points staged in LDS per block (== M-chunk)

// For each x point, min squared distance to the block's y-tile; combine
// across M-chunks via atomicMin on the (order-preserving) float bit pattern.
__global__ __launch_bounds__(BLK) void nn_min_kernel(
    const float* __restrict__ X, const float* __restrict__ Y,
    unsigned int* __restrict__ minbits)
{
    __shared__ float4 sy[TILE];
    const int b    = blockIdx.x;   // batch
    const int nblk = blockIdx.y;   // x-chunk  (NP / (BLK*ILP) chunks)
    const int mblk = blockIdx.z;   // y-chunk  (NP / TILE chunks)
    const int tid  = threadIdx.x;

    // Stage y-tile as padded float4 (single ds_read_b128 per point later).
    const float* Yb = Y + ((size_t)b * NP + (size_t)mblk * TILE) * 3;
    #pragma unroll
    for (int i = tid; i < TILE; i += BLK) {
        sy[i] = make_float4(Yb[i * 3 + 0], Yb[i * 3 + 1], Yb[i * 3 + 2], 0.0f);
    }
    __syncthreads();

    // My ILP x-points, strided by BLK for coalesced loads (contiguous 12B/lane).
    const int n0 = nblk * (BLK * ILP) + tid;
    const float* Xb = X + (size_t)b * NP * 3;
    float px[ILP], py[ILP], pz[ILP], mn[ILP];
    #pragma unroll
    for (int p = 0; p < ILP; ++p) {
        const int n = n0 + p * BLK;
        px[p] = Xb[n * 3 + 0];
        py[p] = Xb[n * 3 + 1];
        pz[p] = Xb[n * 3 + 2];
        mn[p] = 3.3e38f;
    }

    #pragma unroll 4
    for (int j = 0; j < TILE; ++j) {
        const float4 y = sy[j];   // wave-uniform -> LDS broadcast, no conflicts
        #pragma unroll
        for (int p = 0; p < ILP; ++p) {
            const float dx = px[p] - y.x;
            const float dy = py[p] - y.y;
            const float dz = pz[p] - y.z;
            const float d  = fmaf(dx, dx, fmaf(dy, dy, dz * dz));
            mn[p] = fminf(mn[p], d);
        }
    }

    unsigned int* mb = minbits + (size_t)b * NP;
    #pragma unroll
    for (int p = 0; p < ILP; ++p) {
        atomicMin(&mb[n0 + p * BLK], __float_as_uint(mn[p]));
    }
}

// sqrt + block reduction + one scaled atomicAdd per block into out[0].
__global__ __launch_bounds__(256) void reduce_kernel(
    const unsigned int* __restrict__ minbits, float* __restrict__ out)
{
    const int idx = blockIdx.x * 256 + threadIdx.x;
    float v = sqrtf(__uint_as_float(minbits[idx]));
    #pragma unroll
    for (int off = 32; off > 0; off >>= 1)
        v += __shfl_down(v, off, 64);

    __shared__ float ws[4];
    const int lane = threadIdx.x & 63;
    const int wid  = threadIdx.x >> 6;
    if (lane == 0) ws[wid] = v;
    __syncthreads();
    if (threadIdx.x == 0) {
        const float s = (ws[0] + ws[1]) + (ws[2] + ws[3]);
        // out = (sum1+sum2) * 1000 / (2 * B * NP);  1000/131072 is exact in fp32.
        atomicAdd(out, s * 0.00762939453125f);
    }
}

extern "C" void kernel_launch(void* const* d_in, const int* in_sizes, int n_in,
                              void* d_out, int out_size, void* d_ws, size_t ws_size,
                              hipStream_t stream)
{
    const float* a1 = (const float*)d_in[0];  // [NB, NP, 3] fp32
    const float* a2 = (const float*)d_in[1];  // [NB, NP, 3] fp32
    float* out = (float*)d_out;               // scalar fp32
    unsigned int* minbits = (unsigned int*)d_ws;  // [2 * NB * NP] uint

    // Init min workspace to 0x7F7F7F7F (~3.39e38, larger than any real d) and out to 0.
    hipMemsetAsync(minbits, 0x7F, (size_t)2 * NB * NP * sizeof(unsigned int), stream);
    hipMemsetAsync(out, 0, sizeof(float), stream);

    dim3 grid(NB, NP / (BLK * ILP), NP / TILE);  // 16 x 4 x 8 = 512 blocks
    nn_min_kernel<<<grid, BLK, 0, stream>>>(a1, a2, minbits);            // dist1: a1 -> a2
    nn_min_kernel<<<grid, BLK, 0, stream>>>(a2, a1, minbits + NB * NP);  // dist2: a2 -> a1

    reduce_kernel<<<(2 * NB * NP) / 256, 256, 0, stream>>>(minbits, out);
}

// Round 2
// 115.858 us; speedup vs baseline: 1.2154x; 1.2154x over previous
//
#include <hip/hip_runtime.h>
#include <math.h>

#define NB   16      // batches
#define NP   4096    // points per cloud (N == M)
#define ILP  4       // x-points per thread
#define BLK  256     // threads per block
#define TILE 512     // y-points staged in LDS per block

// Inner loop is 4 VALU per pair: m = dot(x,y) - 0.5*||y||^2 in 3 FMAs
// (bias stored in LDS w-component), then one fmax. Since d/2 = a - m with
// a = 0.5*||x||^2, min over d == max over m; subtract+clamp happen once per
// block in the epilogue, then cross-block combine via uint atomicMin
// (valid: values clamped non-negative, uint order == float order).
__global__ __launch_bounds__(BLK) void nn_min_kernel(
    const float* __restrict__ A1, const float* __restrict__ A2,
    unsigned int* __restrict__ minbits)
{
    __shared__ float4 sy[TILE];
    const int b    = blockIdx.x;      // batch
    const int nblk = blockIdx.y;      // x-chunk
    const int z    = blockIdx.z;      // dir (bit 3) + y-chunk (bits 0..2)
    const int mblk = z & 7;
    const int dir  = z >> 3;
    const float* X = dir ? A2 : A1;
    const float* Y = dir ? A1 : A2;
    unsigned int* mb = minbits + ((size_t)dir * NB + b) * NP;
    const int tid  = threadIdx.x;

    // Stage y-tile: (yx, yy, yz, -0.5*||y||^2). 12B/lane contiguous loads.
    const float* Yb = Y + ((size_t)b * NP + (size_t)mblk * TILE) * 3;
    #pragma unroll
    for (int i = tid; i < TILE; i += BLK) {
        const float yx = Yb[i * 3 + 0], yy = Yb[i * 3 + 1], yz = Yb[i * 3 + 2];
        sy[i] = make_float4(yx, yy, yz, -0.5f * (yx * yx + yy * yy + yz * yz));
    }
    __syncthreads();

    const int n0 = nblk * (BLK * ILP) + tid;
    const float* Xb = X + (size_t)b * NP * 3;
    float px[ILP], py[ILP], pz[ILP], ax[ILP], mx[ILP];
    #pragma unroll
    for (int p = 0; p < ILP; ++p) {
        const int n = n0 + p * BLK;
        px[p] = Xb[n * 3 + 0];
        py[p] = Xb[n * 3 + 1];
        pz[p] = Xb[n * 3 + 2];
        ax[p] = 0.5f * (px[p] * px[p] + py[p] * py[p] + pz[p] * pz[p]);
        mx[p] = -3.3e38f;
    }

    #pragma unroll 4
    for (int j = 0; j < TILE; ++j) {
        const float4 y = sy[j];   // wave-uniform -> LDS broadcast, no conflicts
        #pragma unroll
        for (int p = 0; p < ILP; ++p) {
            float m = fmaf(px[p], y.x, y.w);   // dot accumulates onto -0.5*||y||^2
            m = fmaf(py[p], y.y, m);
            m = fmaf(pz[p], y.z, m);
            mx[p] = fmaxf(mx[p], m);
        }
    }

    #pragma unroll
    for (int p = 0; p < ILP; ++p) {
        const float e = fmaxf(ax[p] - mx[p], 0.0f);   // = d_min/2 over this tile
        atomicMin(&mb[n0 + p * BLK], __float_as_uint(e));
    }
}

// Single block: grid-stride uint4 loads, sqrt(2e), hierarchical reduce,
// direct write to out[0] (no atomic -> no out memset node).
__global__ __launch_bounds__(1024) void reduce_kernel(
    const unsigned int* __restrict__ minbits, float* __restrict__ out)
{
    const uint4* mb4 = (const uint4*)minbits;
    float s = 0.0f;
    for (int i = threadIdx.x; i < (2 * NB * NP) / 4; i += 1024) {
        const uint4 u = mb4[i];
        s += sqrtf(2.0f * __uint_as_float(u.x)) + sqrtf(2.0f * __uint_as_float(u.y))
           + sqrtf(2.0f * __uint_as_float(u.z)) + sqrtf(2.0f * __uint_as_float(u.w));
    }
    #pragma unroll
    for (int off = 32; off > 0; off >>= 1)
        s += __shfl_down(s, off, 64);

    __shared__ float ws[16];
    const int lane = threadIdx.x & 63;
    const int wid  = threadIdx.x >> 6;
    if (lane == 0) ws[wid] = s;
    __syncthreads();
    if (threadIdx.x == 0) {
        float t = 0.0f;
        #pragma unroll
        for (int w = 0; w < 16; ++w) t += ws[w];
        // out = (sum1+sum2) * 1000 / (2 * B * NP);  1000/131072 exact in fp32.
        out[0] = t * 0.00762939453125f;
    }
}

extern "C" void kernel_launch(void* const* d_in, const int* in_sizes, int n_in,
                              void* d_out, int out_size, void* d_ws, size_t ws_size,
                              hipStream_t stream)
{
    const float* a1 = (const float*)d_in[0];  // [NB, NP, 3] fp32
    const float* a2 = (const float*)d_in[1];  // [NB, NP, 3] fp32
    float* out = (float*)d_out;
    unsigned int* minbits = (unsigned int*)d_ws;  // [2, NB, NP] uint

    // 0x7F7F7F7F ~ 3.39e38f: larger than any clamped e, uint-order valid.
    hipMemsetAsync(minbits, 0x7F, (size_t)2 * NB * NP * sizeof(unsigned int), stream);

    dim3 grid(NB, NP / (BLK * ILP), 16);  // 16 x 4 x (2 dir * 8 y-chunks) = 1024 blocks
    nn_min_kernel<<<grid, BLK, 0, stream>>>(a1, a2, minbits);

    reduce_kernel<<<1, 1024, 0, stream>>>(minbits, out);
}